// Round 1
// baseline (530.385 us; speedup 1.0000x reference)
//
#include <hip/hip_runtime.h>

#define NPATCH 1600
#define NHEAD 8
#define DHEAD 64
#define DMODEL 512
#define TBL 6241      // 79*79
#define QKVLD 1536

// ---------------------------------------------------------------------------
// GEMM: C[M][Nout] = A[M][512] @ W[Nout][512]^T   (A,W both K-major row-major)
// tiles 64x64, K-step 16, 256 threads, 4x4 microtile per thread
// ---------------------------------------------------------------------------
__global__ __launch_bounds__(256) void k_gemm_qkv(const float* __restrict__ x,
                                                  const float* __restrict__ w,
                                                  float* __restrict__ c,
                                                  int ldc) {
  __shared__ float As[16][68];
  __shared__ float Bs[16][68];
  const int t = threadIdx.x;
  const int m0 = blockIdx.x * 64;
  const int n0 = blockIdx.y * 64;
  const int tx = t & 15;   // m micro
  const int ty = t >> 4;   // n micro
  const int mr = t >> 2;   // staging row 0..63
  const int k4 = (t & 3) * 4;
  float acc[4][4] = {};
  for (int k0 = 0; k0 < DMODEL; k0 += 16) {
    float4 a4 = *reinterpret_cast<const float4*>(x + (size_t)(m0 + mr) * DMODEL + k0 + k4);
    float4 b4 = *reinterpret_cast<const float4*>(w + (size_t)(n0 + mr) * DMODEL + k0 + k4);
    As[k4 + 0][mr] = a4.x; As[k4 + 1][mr] = a4.y; As[k4 + 2][mr] = a4.z; As[k4 + 3][mr] = a4.w;
    Bs[k4 + 0][mr] = b4.x; Bs[k4 + 1][mr] = b4.y; Bs[k4 + 2][mr] = b4.z; Bs[k4 + 3][mr] = b4.w;
    __syncthreads();
    const float4* As4 = reinterpret_cast<const float4*>(&As[0][0]);
    const float4* Bs4 = reinterpret_cast<const float4*>(&Bs[0][0]);
#pragma unroll
    for (int kk = 0; kk < 16; ++kk) {
      float4 av = As4[kk * 17 + tx];
      float4 bv = Bs4[kk * 17 + ty];
      acc[0][0] += av.x * bv.x; acc[0][1] += av.x * bv.y; acc[0][2] += av.x * bv.z; acc[0][3] += av.x * bv.w;
      acc[1][0] += av.y * bv.x; acc[1][1] += av.y * bv.y; acc[1][2] += av.y * bv.z; acc[1][3] += av.y * bv.w;
      acc[2][0] += av.z * bv.x; acc[2][1] += av.z * bv.y; acc[2][2] += av.z * bv.z; acc[2][3] += av.z * bv.w;
      acc[3][0] += av.w * bv.x; acc[3][1] += av.w * bv.y; acc[3][2] += av.w * bv.z; acc[3][3] += av.w * bv.w;
    }
    __syncthreads();
  }
#pragma unroll
  for (int i = 0; i < 4; ++i) {
    float4 o;
    o.x = acc[i][0]; o.y = acc[i][1]; o.z = acc[i][2]; o.w = acc[i][3];
    *reinterpret_cast<float4*>(c + (size_t)(m0 + tx * 4 + i) * ldc + n0 + ty * 4) = o;
  }
}

// out = (out0 @ w_out^T + b_out) * (prob<0.9)
__global__ __launch_bounds__(256) void k_gemm_out(const float* __restrict__ a,
                                                  const float* __restrict__ w,
                                                  const float* __restrict__ bias,
                                                  const float* __restrict__ prob,
                                                  float* __restrict__ outp) {
  __shared__ float As[16][68];
  __shared__ float Bs[16][68];
  const int t = threadIdx.x;
  const int m0 = blockIdx.x * 64;
  const int n0 = blockIdx.y * 64;
  const int tx = t & 15;
  const int ty = t >> 4;
  const int mr = t >> 2;
  const int k4 = (t & 3) * 4;
  float acc[4][4] = {};
  for (int k0 = 0; k0 < DMODEL; k0 += 16) {
    float4 a4 = *reinterpret_cast<const float4*>(a + (size_t)(m0 + mr) * DMODEL + k0 + k4);
    float4 b4 = *reinterpret_cast<const float4*>(w + (size_t)(n0 + mr) * DMODEL + k0 + k4);
    As[k4 + 0][mr] = a4.x; As[k4 + 1][mr] = a4.y; As[k4 + 2][mr] = a4.z; As[k4 + 3][mr] = a4.w;
    Bs[k4 + 0][mr] = b4.x; Bs[k4 + 1][mr] = b4.y; Bs[k4 + 2][mr] = b4.z; Bs[k4 + 3][mr] = b4.w;
    __syncthreads();
    const float4* As4 = reinterpret_cast<const float4*>(&As[0][0]);
    const float4* Bs4 = reinterpret_cast<const float4*>(&Bs[0][0]);
#pragma unroll
    for (int kk = 0; kk < 16; ++kk) {
      float4 av = As4[kk * 17 + tx];
      float4 bv = Bs4[kk * 17 + ty];
      acc[0][0] += av.x * bv.x; acc[0][1] += av.x * bv.y; acc[0][2] += av.x * bv.z; acc[0][3] += av.x * bv.w;
      acc[1][0] += av.y * bv.x; acc[1][1] += av.y * bv.y; acc[1][2] += av.y * bv.z; acc[1][3] += av.y * bv.w;
      acc[2][0] += av.z * bv.x; acc[2][1] += av.z * bv.y; acc[2][2] += av.z * bv.z; acc[2][3] += av.z * bv.w;
      acc[3][0] += av.w * bv.x; acc[3][1] += av.w * bv.y; acc[3][2] += av.w * bv.z; acc[3][3] += av.w * bv.w;
    }
    __syncthreads();
  }
#pragma unroll
  for (int i = 0; i < 4; ++i) {
    const int row = m0 + tx * 4 + i;
    const bool sel = prob[row] < 0.9f;
    float4 o;
    o.x = acc[i][0] + bias[n0 + ty * 4 + 0];
    o.y = acc[i][1] + bias[n0 + ty * 4 + 1];
    o.z = acc[i][2] + bias[n0 + ty * 4 + 2];
    o.w = acc[i][3] + bias[n0 + ty * 4 + 3];
    if (!sel) { o.x = 0.f; o.y = 0.f; o.z = 0.f; o.w = 0.f; }
    *reinterpret_cast<float4*>(outp + (size_t)row * DMODEL + n0 + ty * 4) = o;
  }
}

// tprod[h][i] = table1[i][h] * table2[i][h]
__global__ void k_tprod(const float* __restrict__ t1, const float* __restrict__ t2,
                        float* __restrict__ tp) {
  const int o = blockIdx.x * 256 + threadIdx.x;
  if (o < NHEAD * TBL) {
    const int h = o / TBL;
    const int i = o - h * TBL;
    tp[o] = t1[i * NHEAD + h] * t2[i * NHEAD + h];
  }
}

// ---------------------------------------------------------------------------
// Fused attention: one block = (head h, 8 query rows). 256 threads.
// Writes raw dots0 into attn0 (normalized later by k_norm), and the pruned
// attention @ V result into out0 (pre output-projection).
// ---------------------------------------------------------------------------
__global__ __launch_bounds__(256) void k_attn(const float* __restrict__ qkv,
                                              const float* __restrict__ tprod,
                                              const float* __restrict__ headsita,
                                              const float* __restrict__ w_thresh,
                                              float* __restrict__ attn0,
                                              float* __restrict__ out0) {
  __shared__ float sfull[8 * 1600];   // full-bias score rows -> exp vals -> attn_p
  __shared__ float skq[4096];         // K chunk [16][64] float4; reused as PV partials [4][8][64]
  __shared__ float qbuf[8 * 68];
  const int t = threadIdx.x;
  const int h = blockIdx.y;
  const int n0 = blockIdx.x * 8;

  // --- load Q rows ---
#pragma unroll
  for (int rep = 0; rep < 2; ++rep) {
    const int e = t + rep * 256;
    const int r = e >> 6, dd = e & 63;
    qbuf[r * 68 + dd] = qkv[(size_t)(n0 + r) * QKVLD + h * DHEAD + dd];
  }
  __syncthreads();

  // --- per-row threshold factor: sigmoid(q . w_thresh) * sigmoid(-2) ---
  const int grp = t >> 5;   // row 0..7
  const int lane = t & 31;
  float thr;
  {
    float p = qbuf[grp * 68 + lane] * w_thresh[lane] +
              qbuf[grp * 68 + 32 + lane] * w_thresh[32 + lane];
#pragma unroll
    for (int s = 16; s; s >>= 1) p += __shfl_xor(p, s, 32);
    thr = (1.0f / (1.0f + __expf(-p))) * 0.11920292202211755f;
  }
  const float hs = headsita[h];
  const float fac = 1.0f / (2.0f * hs * hs + 1e-6f);

  // --- scores: dots0 (-> attn0 raw) and dots0+bias+0.01*pos (-> sfull) ---
  const int m_lane = t & 63;
  const int wv = t >> 6;
  const int rA = wv * 2, rB = rA + 1;
  const int nA = n0 + rA, nB = n0 + rB;
  const int nhA = nA / 40, nwA = nA % 40;
  const int nhB = nB / 40, nwB = nB % 40;
  float4* skq4 = reinterpret_cast<float4*>(skq);
  const float4* qb4 = reinterpret_cast<const float4*>(qbuf);

  for (int mc = 0; mc < 25; ++mc) {
    const int m0 = mc * 64;
#pragma unroll
    for (int i = 0; i < 4; ++i) {
      const int f = t + i * 256;
      const int kr = f >> 4, c4 = f & 15;
      skq4[c4 * 64 + kr] = *reinterpret_cast<const float4*>(
          qkv + (size_t)(m0 + kr) * QKVLD + DMODEL + h * DHEAD + c4 * 4);
    }
    __syncthreads();
    float acc0 = 0.f, acc1 = 0.f;
#pragma unroll
    for (int d4 = 0; d4 < 16; ++d4) {
      const float4 kv = skq4[d4 * 64 + m_lane];
      const float4 qa = qb4[rA * 17 + d4];
      const float4 qb = qb4[rB * 17 + d4];
      acc0 = fmaf(kv.x, qa.x, acc0); acc0 = fmaf(kv.y, qa.y, acc0);
      acc0 = fmaf(kv.z, qa.z, acc0); acc0 = fmaf(kv.w, qa.w, acc0);
      acc1 = fmaf(kv.x, qb.x, acc1); acc1 = fmaf(kv.y, qb.y, acc1);
      acc1 = fmaf(kv.z, qb.z, acc1); acc1 = fmaf(kv.w, qb.w, acc1);
    }
    const int m = m0 + m_lane;
    const int mh = m / 40, mw = m - mh * 40;
    {
      const float s0 = acc0 * 0.125f;
      attn0[(size_t)(h * NPATCH + nA) * NPATCH + m] = s0;
      const int dh = nhA - mh, dw = nwA - mw;
      const float fdh = (float)dh * 0.025f;
      const float fdwa = (float)dw * 0.025f;
      const float fdwb = (float)dw * (1.0f / 96.0f);
      const float dis = fdh * fdh + fdwa * fdwa + fdwb * fdwb;
      const float bias = tprod[h * TBL + (dh + 39) * 79 + (dw + 39)];
      sfull[rA * 1600 + m] = s0 + bias + 0.01f * __expf(-fac * dis);
    }
    {
      const float s0 = acc1 * 0.125f;
      attn0[(size_t)(h * NPATCH + nB) * NPATCH + m] = s0;
      const int dh = nhB - mh, dw = nwB - mw;
      const float fdh = (float)dh * 0.025f;
      const float fdwa = (float)dw * 0.025f;
      const float fdwb = (float)dw * (1.0f / 96.0f);
      const float dis = fdh * fdh + fdwa * fdwa + fdwb * fdwb;
      const float bias = tprod[h * TBL + (dh + 39) * 79 + (dw + 39)];
      sfull[rB * 1600 + m] = s0 + bias + 0.01f * __expf(-fac * dis);
    }
    __syncthreads();
  }

  // --- softmax + min/max + threshold prune + renorm (per row, 32 lanes) ---
  {
    float* row = sfull + grp * 1600;
    float lmax = -3.4e38f;
    for (int i = lane; i < 1600; i += 32) lmax = fmaxf(lmax, row[i]);
#pragma unroll
    for (int s = 16; s; s >>= 1) lmax = fmaxf(lmax, __shfl_xor(lmax, s, 32));
    float lsum = 0.f, vmin = 3.4e38f;
    for (int i = lane; i < 1600; i += 32) {
      const float v = __expf(row[i] - lmax);
      row[i] = v;
      lsum += v;
      vmin = fminf(vmin, v);
    }
#pragma unroll
    for (int s = 16; s; s >>= 1) {
      lsum += __shfl_xor(lsum, s, 32);
      vmin = fminf(vmin, __shfl_xor(vmin, s, 32));
    }
    const float aMax = 1.0f / lsum;          // exp(0)/sum
    const float aMin = vmin / lsum;
    const float thresh = aMin + thr * (aMax - aMin);
    float ldeno = 0.f;
    for (int i = lane; i < 1600; i += 32) {
      const float aat = row[i] / lsum;
      if (aat > thresh) ldeno += aat;
    }
#pragma unroll
    for (int s = 16; s; s >>= 1) ldeno += __shfl_xor(ldeno, s, 32);
    const float rs = 1.0f / (ldeno + 1e-6f);
    for (int i = lane; i < 1600; i += 32) {
      const float aat = row[i] / lsum;
      row[i] = (aat > thresh) ? aat * rs : 0.f;
    }
  }
  __syncthreads();

  // --- PV: out0[r][d] = sum_m attn_p[r][m] * V[m][d] ---
  const int d = t & 63;
  const int g = t >> 6;
  float acc[8] = {0.f, 0.f, 0.f, 0.f, 0.f, 0.f, 0.f, 0.f};
  const float* vcol = qkv + 2 * DMODEL + h * DHEAD + d;
  const float4* sf4 = reinterpret_cast<const float4*>(sfull);
  for (int m = g * 400; m < g * 400 + 400; m += 4) {
    const float v0 = vcol[(size_t)(m + 0) * QKVLD];
    const float v1 = vcol[(size_t)(m + 1) * QKVLD];
    const float v2 = vcol[(size_t)(m + 2) * QKVLD];
    const float v3 = vcol[(size_t)(m + 3) * QKVLD];
#pragma unroll
    for (int r = 0; r < 8; ++r) {
      const float4 ap = sf4[(r * 1600 + m) >> 2];
      acc[r] = fmaf(ap.x, v0, acc[r]);
      acc[r] = fmaf(ap.y, v1, acc[r]);
      acc[r] = fmaf(ap.z, v2, acc[r]);
      acc[r] = fmaf(ap.w, v3, acc[r]);
    }
  }
  float* part = skq;  // [4 groups][8 rows][64]
#pragma unroll
  for (int r = 0; r < 8; ++r) part[(g * 8 + r) * 64 + d] = acc[r];
  __syncthreads();
#pragma unroll
  for (int rep = 0; rep < 2; ++rep) {
    const int e = t + rep * 256;
    const int r = e >> 6, dd = e & 63;
    const float s = part[(0 + r) * 64 + dd] + part[(8 + r) * 64 + dd] +
                    part[(16 + r) * 64 + dd] + part[(24 + r) * 64 + dd];
    out0[(size_t)(n0 + r) * DMODEL + h * DHEAD + dd] = s;
  }
}

// row-softmax of raw dots0, in place. one block per (h,n) row.
__global__ __launch_bounds__(256) void k_norm(float* __restrict__ attn0) {
  __shared__ float buf[1600];
  __shared__ float red[4];
  const int t = threadIdx.x;
  float* base = attn0 + (size_t)blockIdx.x * 1600;
  float lmax = -3.4e38f;
  for (int i = t; i < 1600; i += 256) {
    const float v = base[i];
    buf[i] = v;
    lmax = fmaxf(lmax, v);
  }
#pragma unroll
  for (int s = 32; s; s >>= 1) lmax = fmaxf(lmax, __shfl_xor(lmax, s, 64));
  if ((t & 63) == 0) red[t >> 6] = lmax;
  __syncthreads();
  const float M = fmaxf(fmaxf(red[0], red[1]), fmaxf(red[2], red[3]));
  float lsum = 0.f;
  for (int i = t; i < 1600; i += 256) {
    const float v = __expf(buf[i] - M);
    buf[i] = v;
    lsum += v;
  }
#pragma unroll
  for (int s = 32; s; s >>= 1) lsum += __shfl_xor(lsum, s, 64);
  __syncthreads();
  if ((t & 63) == 0) red[t >> 6] = lsum;
  __syncthreads();
  const float S = red[0] + red[1] + red[2] + red[3];
  for (int i = t; i < 1600; i += 256) base[i] = buf[i] / S;
}

extern "C" void kernel_launch(void* const* d_in, const int* in_sizes, int n_in,
                              void* d_out, int out_size, void* d_ws, size_t ws_size,
                              hipStream_t stream) {
  const float* x        = (const float*)d_in[0];
  const float* prob     = (const float*)d_in[1];
  const float* w_qkv    = (const float*)d_in[2];
  const float* table1   = (const float*)d_in[3];
  const float* table2   = (const float*)d_in[4];
  const float* headsita = (const float*)d_in[5];
  const float* w_thresh = (const float*)d_in[6];
  const float* w_out    = (const float*)d_in[7];
  const float* b_out    = (const float*)d_in[8];

  float* out   = (float*)d_out;
  float* attn0 = out + (size_t)NPATCH * DMODEL;        // 819200 onward

  float* qkvb  = (float*)d_ws;                          // [1600][1536]
  float* out0b = qkvb + (size_t)NPATCH * QKVLD;         // [1600][512]
  float* tpb   = out0b + (size_t)NPATCH * DMODEL;       // [8][6241]

  k_gemm_qkv<<<dim3(25, 24), 256, 0, stream>>>(x, w_qkv, qkvb, QKVLD);
  k_tprod<<<dim3((NHEAD * TBL + 255) / 256), 256, 0, stream>>>(table1, table2, tpb);
  k_attn<<<dim3(200, NHEAD), 256, 0, stream>>>(qkvb, tpb, headsita, w_thresh, attn0, out0b);
  k_norm<<<dim3(NHEAD * NPATCH), 256, 0, stream>>>(attn0);
  k_gemm_out<<<dim3(25, 8), 256, 0, stream>>>(out0b, w_out, b_out, prob, out);
}